// Round 10
// baseline (951.518 us; speedup 1.0000x reference)
//
#include <hip/hip_runtime.h>
#include <hip/hip_bf16.h>

// ---------------------------------------------------------------------------
// GCN via associativity:  spmm(H) @ W == spmm(H @ W)
//   D0 = X @ W0T   (f16)  ; A = gelu(spmm(D0) + b0) -> bf16 hi/lo
//   D1 = A @ W1T   (f16)  ; B = gelu(spmm(D1) + b1) -> bf16 hi/lo
//   D2 = B @ W2T   (f16)  ; out = spmm(D2) + b2     (fp32)
// Dense on MFMA via split-bf16 (x = hi+lo, 3 MFMA products, fp32 acc).
// Dense kernel: NO LDS. W hi/lo (256KB) is L1/L2-resident; fragments loaded
// directly from global. 4 waves partition cols, RT=4 row-frags/wave,
// A prefetched one k-step ahead. No barriers -> latency hidden by occupancy.
// SpMM gathers f16 payloads (512B/edge): halves dominant random-gather bytes.
// ---------------------------------------------------------------------------

typedef float f32x4 __attribute__((ext_vector_type(4)));
typedef float f32x2 __attribute__((ext_vector_type(2)));
typedef short s16x4 __attribute__((ext_vector_type(4)));
typedef short bf16x8 __attribute__((ext_vector_type(8)));
typedef _Float16 h16x4 __attribute__((ext_vector_type(4)));
typedef _Float16 h16x2 __attribute__((ext_vector_type(2)));

__device__ __forceinline__ unsigned short f2bf(float x) {   // RNE
    unsigned u = __float_as_uint(x);
    return (unsigned short)((u + 0x7fff + ((u >> 16) & 1)) >> 16);
}
__device__ __forceinline__ float bf2f(unsigned short b) {
    return __uint_as_float(((unsigned)b) << 16);
}

__device__ __forceinline__ float gelu_fast(float x) {
    float u = 0.7978845608028654f * (x + 0.044715f * x * x * x);
    return x / (1.0f + __expf(-2.0f * u));
}

__global__ void count_kernel(const int* __restrict__ row, int* __restrict__ cnt, int e) {
    int i = blockIdx.x * blockDim.x + threadIdx.x;
    if (i < e) atomicAdd(&cnt[row[i]], 1);
}

__global__ void rnorm_kernel(const int* __restrict__ cnt, float* __restrict__ rnorm, int n) {
    int i = blockIdx.x * blockDim.x + threadIdx.x;
    if (i < n) rnorm[i] = rsqrtf((float)(cnt[i] + 1));
}

__global__ void scan1_kernel(const int* __restrict__ cnt, int* __restrict__ rowptr,
                             int* __restrict__ bsum, int n) {
    __shared__ int s[1024];
    int t = threadIdx.x;
    int i = blockIdx.x * 1024 + t;
    int v = (i < n) ? cnt[i] : 0;
    s[t] = v;
    __syncthreads();
    for (int off = 1; off < 1024; off <<= 1) {
        int x = (t >= off) ? s[t - off] : 0;
        __syncthreads();
        s[t] += x;
        __syncthreads();
    }
    if (i < n) rowptr[i] = s[t] - v;
    if (t == 1023) bsum[blockIdx.x] = s[1023];
}

__global__ void scan2_kernel(int* bsum, int nb) {
    if (threadIdx.x == 0 && blockIdx.x == 0) {
        int a = 0;
        for (int b = 0; b < nb; ++b) { int v = bsum[b]; bsum[b] = a; a += v; }
    }
}

__global__ void scan3_kernel(int* __restrict__ rowptr, const int* __restrict__ bsum, int n, int e) {
    int i = blockIdx.x * blockDim.x + threadIdx.x;
    if (i < n) rowptr[i] += bsum[i >> 10];
    if (i == 0) rowptr[n] = e;
}

__global__ void fill_kernel(const int* __restrict__ row, const int* __restrict__ col,
                            const int* __restrict__ rowptr, int* __restrict__ fillc,
                            const float* __restrict__ rnorm,
                            int2* __restrict__ meta, int e) {
    int i = blockIdx.x * blockDim.x + threadIdx.x;
    if (i >= e) return;
    int r = row[i], c = col[i];
    int pos = rowptr[r] + atomicAdd(&fillc[r], 1);
    float w = rnorm[r] * rnorm[c];
    meta[pos] = make_int2(c, __float_as_int(w));
}

// fp32 -> (bf16 hi, bf16 lo) elementwise (weights only; X split fused in dense)
__global__ void split_kernel(const float* __restrict__ in,
                             unsigned short* __restrict__ hi,
                             unsigned short* __restrict__ lo, int total4) {
    int i = blockIdx.x * blockDim.x + threadIdx.x;
    if (i >= total4) return;
    f32x4 x = *(const f32x4*)(in + (size_t)i * 4);
    s16x4 h, l;
#pragma unroll
    for (int q = 0; q < 4; ++q) {
        unsigned short hb = f2bf(x[q]);
        h[q] = (short)hb;
        l[q] = (short)f2bf(x[q] - bf2f(hb));
    }
    *(s16x4*)(hi + (size_t)i * 4) = h;
    *(s16x4*)(lo + (size_t)i * 4) = l;
}

template <int WPL> struct HVecT;
template <> struct HVecT<4> { using T = h16x4; };
template <> struct HVecT<2> { using T = h16x2; };

// one wave per row; 64 lanes x WPL f16 gathers. fp32 accumulate.
// Bias + optional gelu fused; SPLIT writes bf16 hi/lo for the MFMA dense.
template <int WPL, bool GELU, bool SPLIT>
__global__ __launch_bounds__(256) void spmm_kernel(const _Float16* __restrict__ in,
                                                   float* __restrict__ out,
                                                   unsigned short* __restrict__ ohi,
                                                   unsigned short* __restrict__ olo,
                                                   const int* __restrict__ rowptr,
                                                   const int2* __restrict__ meta,
                                                   const float* __restrict__ rnorm,
                                                   const float* __restrict__ bias, int n) {
    using hvec_t = typename HVecT<WPL>::T;
    constexpr int RW = 64 * WPL;
    int wid = blockIdx.x * 4 + (threadIdx.x >> 6);
    if (wid >= n) return;
    int lane = threadIdx.x & 63;
    const _Float16* lanebase = in + lane * WPL;

    float rn = rnorm[wid];
    float sw = rn * rn;   // self-loop weight
    float acc[WPL];
    {
        hvec_t a = *(const hvec_t*)(lanebase + (size_t)wid * RW);
#pragma unroll
        for (int q = 0; q < WPL; ++q) acc[q] = sw * (float)a[q];
    }

    int e0 = rowptr[wid], e1 = rowptr[wid + 1];
    int e = e0;
    int nbatch = (e1 - e0) >> 3;
    if (nbatch > 0) {
        int2 m[8];
#pragma unroll
        for (int u = 0; u < 8; ++u) m[u] = meta[e + u];
        for (int b = 0; b < nbatch; ++b) {
            hvec_t v[8];
#pragma unroll
            for (int u = 0; u < 8; ++u) v[u] = *(const hvec_t*)(lanebase + (size_t)m[u].x * RW);
            int2 mn[8];
            bool more = (b + 1 < nbatch);
            if (more) {
#pragma unroll
                for (int u = 0; u < 8; ++u) mn[u] = meta[e + 8 + u];
            }
#pragma unroll
            for (int u = 0; u < 8; ++u) {
                float w = __int_as_float(m[u].y);
#pragma unroll
                for (int q = 0; q < WPL; ++q) acc[q] = fmaf(w, (float)v[u][q], acc[q]);
            }
            if (more) {
#pragma unroll
                for (int u = 0; u < 8; ++u) m[u] = mn[u];
            }
            e += 8;
        }
    }
    for (; e < e1; ++e) {
        int2 m = meta[e];
        hvec_t v = *(const hvec_t*)(lanebase + (size_t)m.x * RW);
        float w = __int_as_float(m.y);
#pragma unroll
        for (int q = 0; q < WPL; ++q) acc[q] = fmaf(w, (float)v[q], acc[q]);
    }

    if (SPLIT) {
        const f32x4* bv4 = (const f32x4*)(bias + lane * WPL);
        f32x4 bv = *bv4;
        s16x4 h, l;
#pragma unroll
        for (int q = 0; q < WPL; ++q) {
            float x = acc[q] + bv[q];
            float y = GELU ? gelu_fast(x) : x;
            unsigned short hb = f2bf(y);
            h[q] = (short)hb;
            l[q] = (short)f2bf(y - bf2f(hb));
        }
        *(s16x4*)(ohi + (size_t)wid * RW + lane * WPL) = h;
        *(s16x4*)(olo + (size_t)wid * RW + lane * WPL) = l;
    } else {
        f32x2 bv = *(const f32x2*)(bias + lane * WPL);
        f32x2 o;
#pragma unroll
        for (int q = 0; q < WPL; ++q) {
            float x = acc[q] + bv[q];
            o[q] = GELU ? gelu_fast(x) : x;
        }
        __builtin_nontemporal_store(o, (f32x2*)(out + (size_t)wid * RW + lane * WPL));
    }
}

// out[N][DO](f16) = A[N][256] @ (Whi+Wlo)[DO][256]^T via 3 bf16 MFMAs.
// No LDS/barriers: W fragments read directly from global (L1/L2-resident,
// 256KB total). 4 waves partition columns (NTW tiles each); each wave does
// RT=4 row-fragments (block = 64 rows x DO cols). A hi/lo prefetched one
// 32-k step ahead so streaming-load latency hides under the MFMA block.
// Fragment layouts (16x16x32 bf16): A idx=lane&15(row), k=(lane>>4)*8+j;
// B consumes W[n][k] natively; C col=lane&15, row=(lane>>4)*4+reg.
template <int DO, bool SPLITIN>
__global__ __launch_bounds__(256, 3) void dense_mfma_kernel(
        const unsigned short* __restrict__ Ahi, const unsigned short* __restrict__ Alo,
        const float* __restrict__ Af32,
        const unsigned short* __restrict__ Whi, const unsigned short* __restrict__ Wlo,
        _Float16* __restrict__ out, int n) {
    constexpr int NTW = DO / 64;   // col-tiles per wave: 4 (DO=256) / 2 (128)
    constexpr int RT = 4;          // row-frags per wave (64 rows/block)

    int t = threadIdx.x;
    int lane = t & 63;
    int w = t >> 6;
    int r = lane & 15;
    int g = lane >> 4;
    int row0 = blockIdx.x * 64;

    int aoff[RT];
#pragma unroll
    for (int rt = 0; rt < RT; ++rt) {
        int arow = row0 + rt * 16 + r;
        if (arow >= n) arow = n - 1;          // clamp (tail block)
        aoff[rt] = arow * 256 + g * 8;
    }
    int woff[NTW];
#pragma unroll
    for (int nt = 0; nt < NTW; ++nt)
        woff[nt] = ((w * NTW + nt) * 16 + r) * 256 + g * 8;

    f32x4 acc[RT][NTW];
#pragma unroll
    for (int rt = 0; rt < RT; ++rt)
#pragma unroll
        for (int nt = 0; nt < NTW; ++nt) acc[rt][nt] = (f32x4){0.f, 0.f, 0.f, 0.f};

    // current A fragments (bf16 hi/lo)
    bf16x8 ah[RT], al[RT];
#pragma unroll
    for (int rt = 0; rt < RT; ++rt) {
        if (SPLITIN) {
            f32x4 x0 = *(const f32x4*)&Af32[aoff[rt]];
            f32x4 x1 = *(const f32x4*)&Af32[aoff[rt] + 4];
#pragma unroll
            for (int q = 0; q < 4; ++q) {
                unsigned short hb = f2bf(x0[q]);
                ah[rt][q] = (short)hb;
                al[rt][q] = (short)f2bf(x0[q] - bf2f(hb));
                unsigned short hb1 = f2bf(x1[q]);
                ah[rt][q + 4] = (short)hb1;
                al[rt][q + 4] = (short)f2bf(x1[q] - bf2f(hb1));
            }
        } else {
            ah[rt] = *(const bf16x8*)&Ahi[aoff[rt]];
            al[rt] = *(const bf16x8*)&Alo[aoff[rt]];
        }
    }

#pragma unroll 1
    for (int s = 0; s < 8; ++s) {             // 8 k-steps of 32
        int kb = s * 32;
        // prefetch next step's A
        f32x4 nf[RT][2];
        bf16x8 nh[RT], nl[RT];
        if (s < 7) {
#pragma unroll
            for (int rt = 0; rt < RT; ++rt) {
                if (SPLITIN) {
                    nf[rt][0] = *(const f32x4*)&Af32[aoff[rt] + kb + 32];
                    nf[rt][1] = *(const f32x4*)&Af32[aoff[rt] + kb + 36];
                } else {
                    nh[rt] = *(const bf16x8*)&Ahi[aoff[rt] + kb + 32];
                    nl[rt] = *(const bf16x8*)&Alo[aoff[rt] + kb + 32];
                }
            }
        }
        // compute: per col-tile load W frags (L1/L2-hot) and do RT*3 MFMA
#pragma unroll
        for (int nt = 0; nt < NTW; ++nt) {
            bf16x8 wh = *(const bf16x8*)&Whi[woff[nt] + kb];
            bf16x8 wl = *(const bf16x8*)&Wlo[woff[nt] + kb];
#pragma unroll
            for (int rt = 0; rt < RT; ++rt) {
                acc[rt][nt] = __builtin_amdgcn_mfma_f32_16x16x32_bf16(ah[rt], wh, acc[rt][nt], 0, 0, 0);
                acc[rt][nt] = __builtin_amdgcn_mfma_f32_16x16x32_bf16(ah[rt], wl, acc[rt][nt], 0, 0, 0);
                acc[rt][nt] = __builtin_amdgcn_mfma_f32_16x16x32_bf16(al[rt], wh, acc[rt][nt], 0, 0, 0);
            }
        }
        // swap in prefetched A
        if (s < 7) {
#pragma unroll
            for (int rt = 0; rt < RT; ++rt) {
                if (SPLITIN) {
#pragma unroll
                    for (int q = 0; q < 4; ++q) {
                        unsigned short hb = f2bf(nf[rt][0][q]);
                        ah[rt][q] = (short)hb;
                        al[rt][q] = (short)f2bf(nf[rt][0][q] - bf2f(hb));
                        unsigned short hb1 = f2bf(nf[rt][1][q]);
                        ah[rt][q + 4] = (short)hb1;
                        al[rt][q + 4] = (short)f2bf(nf[rt][1][q] - bf2f(hb1));
                    }
                } else {
                    ah[rt] = nh[rt];
                    al[rt] = nl[rt];
                }
            }
        }
    }

    // write-out: C frag col=lane&15 (=r), row=g*4+j within each 16-row tile
#pragma unroll
    for (int rt = 0; rt < RT; ++rt) {
#pragma unroll
        for (int nt = 0; nt < NTW; ++nt) {
            int ccol = (w * NTW + nt) * 16 + r;
#pragma unroll
            for (int j = 0; j < 4; ++j) {
                int rr = row0 + rt * 16 + g * 4 + j;
                if (rr < n) out[(size_t)rr * DO + ccol] = (_Float16)acc[rt][nt][j];
            }
        }
    }
}

extern "C" void kernel_launch(void* const* d_in, const int* in_sizes, int n_in,
                              void* d_out, int out_size, void* d_ws, size_t ws_size,
                              hipStream_t stream) {
    const float* X  = (const float*)d_in[0];
    const int* row  = (const int*)d_in[1];
    const int* col  = (const int*)d_in[2];
    const float* W0 = (const float*)d_in[3];
    const float* b0 = (const float*)d_in[4];
    const float* W1 = (const float*)d_in[5];
    const float* b1 = (const float*)d_in[6];
    const float* W2 = (const float*)d_in[7];
    const float* b2 = (const float*)d_in[8];

    int n = in_sizes[0] / 256;   // 100000
    int e = in_sizes[1];         // 1600000

    char* ws = (char*)d_ws;
    size_t off = 0;
    auto alloc = [&](size_t bytes) {
        void* p = ws + off;
        off += (bytes + 255) & ~(size_t)255;
        return p;
    };
    unsigned short* HI   = (unsigned short*)alloc((size_t)n * 256 * 2);
    unsigned short* LO   = (unsigned short*)alloc((size_t)n * 256 * 2);
    _Float16*       Dh   = (_Float16*)alloc((size_t)n * 256 * 2);
    unsigned short* W0hi = (unsigned short*)alloc(256 * 256 * 2);
    unsigned short* W0lo = (unsigned short*)alloc(256 * 256 * 2);
    unsigned short* W1hi = (unsigned short*)alloc(256 * 256 * 2);
    unsigned short* W1lo = (unsigned short*)alloc(256 * 256 * 2);
    unsigned short* W2hi = (unsigned short*)alloc(256 * 128 * 2);
    unsigned short* W2lo = (unsigned short*)alloc(256 * 128 * 2);
    int*   cnt    = (int*)alloc((size_t)n * 4);
    int*   fillc  = (int*)alloc((size_t)n * 4);
    float* rnorm  = (float*)alloc((size_t)n * 4);
    int*   rowptr = (int*)alloc(((size_t)n + 1) * 4);
    int*   bsum   = (int*)alloc(512);
    int2*  meta   = (int2*)alloc((size_t)e * 8);

    (void)hipMemsetAsync(cnt, 0, (size_t)n * 4, stream);
    (void)hipMemsetAsync(fillc, 0, (size_t)n * 4, stream);

    int gE = (e + 255) / 256;
    int gN = (n + 255) / 256;
    int nb = (n + 1023) / 1024;

    count_kernel<<<gE, 256, 0, stream>>>(row, cnt, e);
    rnorm_kernel<<<gN, 256, 0, stream>>>(cnt, rnorm, n);
    scan1_kernel<<<nb, 1024, 0, stream>>>(cnt, rowptr, bsum, n);
    scan2_kernel<<<1, 64, 0, stream>>>(bsum, nb);
    scan3_kernel<<<gN, 256, 0, stream>>>(rowptr, bsum, n, e);
    fill_kernel<<<gE, 256, 0, stream>>>(row, col, rowptr, fillc, rnorm, meta, e);

    split_kernel<<<(16384 + 255) / 256, 256, 0, stream>>>(W0, W0hi, W0lo, 16384);
    split_kernel<<<(16384 + 255) / 256, 256, 0, stream>>>(W1, W1hi, W1lo, 16384);
    split_kernel<<<(8192 + 255) / 256, 256, 0, stream>>>(W2, W2hi, W2lo, 8192);

    int gS = (n + 3) / 4;       // spmm: 4 waves/block, 1 row/wave
    int gM = (n + 63) / 64;     // dense mfma: 64 rows/block

    // D0 = X @ W0T (X split in-register) ; A = gelu(spmm(D0)+b0) -> bf16 hi/lo
    dense_mfma_kernel<256, true><<<gM, 256, 0, stream>>>(nullptr, nullptr, X, W0hi, W0lo, Dh, n);
    spmm_kernel<4, true, true><<<gS, 256, 0, stream>>>(Dh, nullptr, HI, LO, rowptr, meta, rnorm, b0, n);
    // D1 ; B = gelu(spmm(D1)+b1) -> bf16 hi/lo
    dense_mfma_kernel<256, false><<<gM, 256, 0, stream>>>(HI, LO, nullptr, W1hi, W1lo, Dh, n);
    spmm_kernel<4, true, true><<<gS, 256, 0, stream>>>(Dh, nullptr, HI, LO, rowptr, meta, rnorm, b1, n);
    // D2 (128-wide) ; out = spmm(D2) + b2 (fp32)
    dense_mfma_kernel<128, false><<<gM, 256, 0, stream>>>(HI, LO, nullptr, W2hi, W2lo, Dh, n);
    spmm_kernel<2, false, false><<<gS, 256, 0, stream>>>(Dh, (float*)d_out, nullptr, nullptr, rowptr, meta, rnorm, b2, n);
}

// Round 11
// 800.027 us; speedup vs baseline: 1.1894x; 1.1894x over previous
//
#include <hip/hip_runtime.h>
#include <hip/hip_bf16.h>

// ---------------------------------------------------------------------------
// GCN via associativity:  spmm(H) @ W == spmm(H @ W)
//   D0 = X @ W0T   (f16)  ; A = gelu(spmm(D0) + b0) -> bf16 hi/lo
//   D1 = A @ W1T   (f16)  ; B = gelu(spmm(D1) + b1) -> bf16 hi/lo
//   D2 = B @ W2T   (f16)  ; out = spmm(D2) + b2     (fp32)
// Dense on MFMA via split-bf16 (x = hi+lo, 3 MFMA products, fp32 acc).
// Dense kernel: W hi/lo staged per 64-k chunk into LDS via global_load_lds
// (no staging VGPRs); 4 waves = 2 row-groups x 2 col-halves; RT=4 row-frags
// per wave so each W-fragment LDS read feeds 12 MFMAs (was 3 in the old
// version -> LDS-throughput-bound at MfmaUtil 10%).
// SpMM gathers f16 payloads (512B/edge): halves dominant random-gather bytes.
// ---------------------------------------------------------------------------

typedef float f32x4 __attribute__((ext_vector_type(4)));
typedef float f32x2 __attribute__((ext_vector_type(2)));
typedef short s16x4 __attribute__((ext_vector_type(4)));
typedef short bf16x8 __attribute__((ext_vector_type(8)));
typedef _Float16 h16x4 __attribute__((ext_vector_type(4)));
typedef _Float16 h16x2 __attribute__((ext_vector_type(2)));

__device__ __forceinline__ unsigned short f2bf(float x) {   // RNE
    unsigned u = __float_as_uint(x);
    return (unsigned short)((u + 0x7fff + ((u >> 16) & 1)) >> 16);
}
__device__ __forceinline__ float bf2f(unsigned short b) {
    return __uint_as_float(((unsigned)b) << 16);
}

__device__ __forceinline__ float gelu_fast(float x) {
    float u = 0.7978845608028654f * (x + 0.044715f * x * x * x);
    return x / (1.0f + __expf(-2.0f * u));
}

__global__ void count_kernel(const int* __restrict__ row, int* __restrict__ cnt, int e) {
    int i = blockIdx.x * blockDim.x + threadIdx.x;
    if (i < e) atomicAdd(&cnt[row[i]], 1);
}

__global__ void rnorm_kernel(const int* __restrict__ cnt, float* __restrict__ rnorm, int n) {
    int i = blockIdx.x * blockDim.x + threadIdx.x;
    if (i < n) rnorm[i] = rsqrtf((float)(cnt[i] + 1));
}

__global__ void scan1_kernel(const int* __restrict__ cnt, int* __restrict__ rowptr,
                             int* __restrict__ bsum, int n) {
    __shared__ int s[1024];
    int t = threadIdx.x;
    int i = blockIdx.x * 1024 + t;
    int v = (i < n) ? cnt[i] : 0;
    s[t] = v;
    __syncthreads();
    for (int off = 1; off < 1024; off <<= 1) {
        int x = (t >= off) ? s[t - off] : 0;
        __syncthreads();
        s[t] += x;
        __syncthreads();
    }
    if (i < n) rowptr[i] = s[t] - v;
    if (t == 1023) bsum[blockIdx.x] = s[1023];
}

__global__ void scan2_kernel(int* bsum, int nb) {
    if (threadIdx.x == 0 && blockIdx.x == 0) {
        int a = 0;
        for (int b = 0; b < nb; ++b) { int v = bsum[b]; bsum[b] = a; a += v; }
    }
}

__global__ void scan3_kernel(int* __restrict__ rowptr, const int* __restrict__ bsum, int n, int e) {
    int i = blockIdx.x * blockDim.x + threadIdx.x;
    if (i < n) rowptr[i] += bsum[i >> 10];
    if (i == 0) rowptr[n] = e;
}

__global__ void fill_kernel(const int* __restrict__ row, const int* __restrict__ col,
                            const int* __restrict__ rowptr, int* __restrict__ fillc,
                            const float* __restrict__ rnorm,
                            int2* __restrict__ meta, int e) {
    int i = blockIdx.x * blockDim.x + threadIdx.x;
    if (i >= e) return;
    int r = row[i], c = col[i];
    int pos = rowptr[r] + atomicAdd(&fillc[r], 1);
    float w = rnorm[r] * rnorm[c];
    meta[pos] = make_int2(c, __float_as_int(w));
}

// fp32 -> (bf16 hi, bf16 lo) elementwise (weights only; X split fused in dense)
__global__ void split_kernel(const float* __restrict__ in,
                             unsigned short* __restrict__ hi,
                             unsigned short* __restrict__ lo, int total4) {
    int i = blockIdx.x * blockDim.x + threadIdx.x;
    if (i >= total4) return;
    f32x4 x = *(const f32x4*)(in + (size_t)i * 4);
    s16x4 h, l;
#pragma unroll
    for (int q = 0; q < 4; ++q) {
        unsigned short hb = f2bf(x[q]);
        h[q] = (short)hb;
        l[q] = (short)f2bf(x[q] - bf2f(hb));
    }
    *(s16x4*)(hi + (size_t)i * 4) = h;
    *(s16x4*)(lo + (size_t)i * 4) = l;
}

template <int WPL> struct HVecT;
template <> struct HVecT<4> { using T = h16x4; };
template <> struct HVecT<2> { using T = h16x2; };

// one wave per row; 64 lanes x WPL f16 gathers. fp32 accumulate.
// Bias + optional gelu fused; SPLIT writes bf16 hi/lo for the MFMA dense.
template <int WPL, bool GELU, bool SPLIT>
__global__ __launch_bounds__(256) void spmm_kernel(const _Float16* __restrict__ in,
                                                   float* __restrict__ out,
                                                   unsigned short* __restrict__ ohi,
                                                   unsigned short* __restrict__ olo,
                                                   const int* __restrict__ rowptr,
                                                   const int2* __restrict__ meta,
                                                   const float* __restrict__ rnorm,
                                                   const float* __restrict__ bias, int n) {
    using hvec_t = typename HVecT<WPL>::T;
    constexpr int RW = 64 * WPL;
    int wid = blockIdx.x * 4 + (threadIdx.x >> 6);
    if (wid >= n) return;
    int lane = threadIdx.x & 63;
    const _Float16* lanebase = in + lane * WPL;

    float rn = rnorm[wid];
    float sw = rn * rn;   // self-loop weight
    float acc[WPL];
    {
        hvec_t a = *(const hvec_t*)(lanebase + (size_t)wid * RW);
#pragma unroll
        for (int q = 0; q < WPL; ++q) acc[q] = sw * (float)a[q];
    }

    int e0 = rowptr[wid], e1 = rowptr[wid + 1];
    int e = e0;
    int nbatch = (e1 - e0) >> 3;
    if (nbatch > 0) {
        int2 m[8];
#pragma unroll
        for (int u = 0; u < 8; ++u) m[u] = meta[e + u];
        for (int b = 0; b < nbatch; ++b) {
            hvec_t v[8];
#pragma unroll
            for (int u = 0; u < 8; ++u) v[u] = *(const hvec_t*)(lanebase + (size_t)m[u].x * RW);
            int2 mn[8];
            bool more = (b + 1 < nbatch);
            if (more) {
#pragma unroll
                for (int u = 0; u < 8; ++u) mn[u] = meta[e + 8 + u];
            }
#pragma unroll
            for (int u = 0; u < 8; ++u) {
                float w = __int_as_float(m[u].y);
#pragma unroll
                for (int q = 0; q < WPL; ++q) acc[q] = fmaf(w, (float)v[u][q], acc[q]);
            }
            if (more) {
#pragma unroll
                for (int u = 0; u < 8; ++u) m[u] = mn[u];
            }
            e += 8;
        }
    }
    for (; e < e1; ++e) {
        int2 m = meta[e];
        hvec_t v = *(const hvec_t*)(lanebase + (size_t)m.x * RW);
        float w = __int_as_float(m.y);
#pragma unroll
        for (int q = 0; q < WPL; ++q) acc[q] = fmaf(w, (float)v[q], acc[q]);
    }

    if (SPLIT) {
        const f32x4* bv4 = (const f32x4*)(bias + lane * WPL);
        f32x4 bv = *bv4;
        s16x4 h, l;
#pragma unroll
        for (int q = 0; q < WPL; ++q) {
            float x = acc[q] + bv[q];
            float y = GELU ? gelu_fast(x) : x;
            unsigned short hb = f2bf(y);
            h[q] = (short)hb;
            l[q] = (short)f2bf(y - bf2f(hb));
        }
        *(s16x4*)(ohi + (size_t)wid * RW + lane * WPL) = h;
        *(s16x4*)(olo + (size_t)wid * RW + lane * WPL) = l;
    } else {
        f32x2 bv = *(const f32x2*)(bias + lane * WPL);
        f32x2 o;
#pragma unroll
        for (int q = 0; q < WPL; ++q) {
            float x = acc[q] + bv[q];
            o[q] = GELU ? gelu_fast(x) : x;
        }
        __builtin_nontemporal_store(o, (f32x2*)(out + (size_t)wid * RW + lane * WPL));
    }
}

// out[N][DO](f16) = A[N][256] @ (Whi+Wlo)[DO][256]^T via 3 bf16 MFMAs.
// Block: 4 waves = 2 row-groups x 2 col-halves; each wave RT row-frags x
// DO/2 cols (NT tiles). W hi/lo staged per 64-k chunk into LDS via
// global_load_lds (dest = wave-uniform base + lane*16 -> legal). One wh/wl
// LDS read pair feeds 3*RT MFMAs. A loads issue during the stage phase and
// are drained by the pre-barrier vmcnt(0).
// Fragment layouts (16x16x32 bf16): A row=lane&15, k=(lane>>4)*8+j;
// B consumes W[n][k] natively; C col=lane&15, row=(lane>>4)*4+reg.
template <int DO, int RT, bool SPLITIN>
__global__ __launch_bounds__(256, 2) void dense_mfma_kernel(
        const unsigned short* __restrict__ Ahi, const unsigned short* __restrict__ Alo,
        const float* __restrict__ Af32,
        const unsigned short* __restrict__ Whi, const unsigned short* __restrict__ Wlo,
        _Float16* __restrict__ out, int n) {
    constexpr int KC = 64, NKK = 2, NCH = 4;
    constexpr int NTT = DO / 16;         // total col tiles (16 / 8)
    constexpr int NT = NTT / 2;          // col tiles per wave (8 / 4)
    constexpr int NFRAG = 2 * NTT * NKK; // hi+lo frags per chunk
    constexpr int BM = 2 * RT * 16;      // rows per block
    __shared__ bf16x8 s_w[NFRAG * 64];   // 64KB (DO=256) / 32KB (DO=128)

    int t = threadIdx.x;
    int lane = t & 63;
    int w = t >> 6;
    int r = lane & 15;
    int g = lane >> 4;
    int h = w & 1;                       // col half
    int row0 = blockIdx.x * BM + (w >> 1) * (RT * 16);

    int aoff[RT];
#pragma unroll
    for (int rt = 0; rt < RT; ++rt) {
        int arow = row0 + rt * 16 + r;
        if (arow >= n) arow = n - 1;     // clamp (tail block)
        aoff[rt] = arow * 256 + g * 8;
    }

    f32x4 acc[RT][NT];
#pragma unroll
    for (int rt = 0; rt < RT; ++rt)
#pragma unroll
        for (int nt = 0; nt < NT; ++nt) acc[rt][nt] = (f32x4){0.f, 0.f, 0.f, 0.f};

    bf16x8 ah[RT][NKK], al[RT][NKK];

    for (int c = 0; c < NCH; ++c) {
        int kb = c * KC;
        __syncthreads();                 // previous compute done; LDS reusable
        // stage W hi/lo fragments for this chunk: global -> LDS direct
#pragma unroll
        for (int i = 0; i < NFRAG / 4; ++i) {
            int s = t + i * 256;
            int sl = s & 63;
            int f = s >> 6;              // f = op*NTT*NKK + ntf*NKK + kk
            int kk = f % NKK;
            int ntf = (f / NKK) % NTT;
            int op = f / (NKK * NTT);
            const unsigned short* src = op ? Wlo : Whi;
            const unsigned short* gsrc =
                &src[(size_t)(ntf * 16 + (sl & 15)) * 256 + kb + kk * 32 + ((sl >> 4) << 3)];
            __builtin_amdgcn_global_load_lds(
                (const __attribute__((address_space(1))) void*)gsrc,
                (__attribute__((address_space(3))) void*)&s_w[s], 16, 0, 0);
        }
        // A loads for this chunk (latency hidden under stage + barrier)
#pragma unroll
        for (int rt = 0; rt < RT; ++rt) {
#pragma unroll
            for (int kk = 0; kk < NKK; ++kk) {
                if (SPLITIN) {
                    f32x4 x0 = *(const f32x4*)&Af32[aoff[rt] + kb + kk * 32];
                    f32x4 x1 = *(const f32x4*)&Af32[aoff[rt] + kb + kk * 32 + 4];
#pragma unroll
                    for (int q = 0; q < 4; ++q) {
                        unsigned short hb = f2bf(x0[q]);
                        ah[rt][kk][q] = (short)hb;
                        al[rt][kk][q] = (short)f2bf(x0[q] - bf2f(hb));
                        unsigned short hb1 = f2bf(x1[q]);
                        ah[rt][kk][q + 4] = (short)hb1;
                        al[rt][kk][q + 4] = (short)f2bf(x1[q] - bf2f(hb1));
                    }
                } else {
                    ah[rt][kk] = *(const bf16x8*)&Ahi[aoff[rt] + kb + kk * 32];
                    al[rt][kk] = *(const bf16x8*)&Alo[aoff[rt] + kb + kk * 32];
                }
            }
        }
        __syncthreads();                 // vmcnt(0) drained: LDS + A ready

#pragma unroll
        for (int kk = 0; kk < NKK; ++kk) {
#pragma unroll
            for (int nt = 0; nt < NT; ++nt) {
                int ntf = h * NT + nt;
                bf16x8 wh = s_w[(ntf * NKK + kk) * 64 + lane];
                bf16x8 wl = s_w[((NTT + ntf) * NKK + kk) * 64 + lane];
#pragma unroll
                for (int rt = 0; rt < RT; ++rt) {
                    acc[rt][nt] = __builtin_amdgcn_mfma_f32_16x16x32_bf16(ah[rt][kk], wh, acc[rt][nt], 0, 0, 0);
                    acc[rt][nt] = __builtin_amdgcn_mfma_f32_16x16x32_bf16(ah[rt][kk], wl, acc[rt][nt], 0, 0, 0);
                    acc[rt][nt] = __builtin_amdgcn_mfma_f32_16x16x32_bf16(al[rt][kk], wh, acc[rt][nt], 0, 0, 0);
                }
            }
        }
    }

    // C frag: col=lane&15 (=r), row=g*4+j within each 16-row tile
#pragma unroll
    for (int rt = 0; rt < RT; ++rt) {
#pragma unroll
        for (int nt = 0; nt < NT; ++nt) {
            int ccol = (h * NT + nt) * 16 + r;
#pragma unroll
            for (int j = 0; j < 4; ++j) {
                int rr = row0 + rt * 16 + g * 4 + j;
                if (rr < n) out[(size_t)rr * DO + ccol] = (_Float16)acc[rt][nt][j];
            }
        }
    }
}

extern "C" void kernel_launch(void* const* d_in, const int* in_sizes, int n_in,
                              void* d_out, int out_size, void* d_ws, size_t ws_size,
                              hipStream_t stream) {
    const float* X  = (const float*)d_in[0];
    const int* row  = (const int*)d_in[1];
    const int* col  = (const int*)d_in[2];
    const float* W0 = (const float*)d_in[3];
    const float* b0 = (const float*)d_in[4];
    const float* W1 = (const float*)d_in[5];
    const float* b1 = (const float*)d_in[6];
    const float* W2 = (const float*)d_in[7];
    const float* b2 = (const float*)d_in[8];

    int n = in_sizes[0] / 256;   // 100000
    int e = in_sizes[1];         // 1600000

    char* ws = (char*)d_ws;
    size_t off = 0;
    auto alloc = [&](size_t bytes) {
        void* p = ws + off;
        off += (bytes + 255) & ~(size_t)255;
        return p;
    };
    unsigned short* HI   = (unsigned short*)alloc((size_t)n * 256 * 2);
    unsigned short* LO   = (unsigned short*)alloc((size_t)n * 256 * 2);
    _Float16*       Dh   = (_Float16*)alloc((size_t)n * 256 * 2);
    unsigned short* W0hi = (unsigned short*)alloc(256 * 256 * 2);
    unsigned short* W0lo = (unsigned short*)alloc(256 * 256 * 2);
    unsigned short* W1hi = (unsigned short*)alloc(256 * 256 * 2);
    unsigned short* W1lo = (unsigned short*)alloc(256 * 256 * 2);
    unsigned short* W2hi = (unsigned short*)alloc(256 * 128 * 2);
    unsigned short* W2lo = (unsigned short*)alloc(256 * 128 * 2);
    int*   cnt    = (int*)alloc((size_t)n * 4);
    int*   fillc  = (int*)alloc((size_t)n * 4);
    float* rnorm  = (float*)alloc((size_t)n * 4);
    int*   rowptr = (int*)alloc(((size_t)n + 1) * 4);
    int*   bsum   = (int*)alloc(512);
    int2*  meta   = (int2*)alloc((size_t)e * 8);

    (void)hipMemsetAsync(cnt, 0, (size_t)n * 4, stream);
    (void)hipMemsetAsync(fillc, 0, (size_t)n * 4, stream);

    int gE = (e + 255) / 256;
    int gN = (n + 255) / 256;
    int nb = (n + 1023) / 1024;

    count_kernel<<<gE, 256, 0, stream>>>(row, cnt, e);
    rnorm_kernel<<<gN, 256, 0, stream>>>(cnt, rnorm, n);
    scan1_kernel<<<nb, 1024, 0, stream>>>(cnt, rowptr, bsum, n);
    scan2_kernel<<<1, 64, 0, stream>>>(bsum, nb);
    scan3_kernel<<<gN, 256, 0, stream>>>(rowptr, bsum, n, e);
    fill_kernel<<<gE, 256, 0, stream>>>(row, col, rowptr, fillc, rnorm, meta, e);

    split_kernel<<<(16384 + 255) / 256, 256, 0, stream>>>(W0, W0hi, W0lo, 16384);
    split_kernel<<<(16384 + 255) / 256, 256, 0, stream>>>(W1, W1hi, W1lo, 16384);
    split_kernel<<<(8192 + 255) / 256, 256, 0, stream>>>(W2, W2hi, W2lo, 8192);

    int gS  = (n + 3) / 4;        // spmm: 4 waves/block, 1 row/wave
    int gM0 = (n + 63) / 64;      // dense0: BM=64  (RT=2, fp32 X split fused)
    int gMd = (n + 127) / 128;    // dense1/2: BM=128 (RT=4)

    // D0 = X @ W0T (X split in-register) ; A = gelu(spmm(D0)+b0) -> bf16 hi/lo
    dense_mfma_kernel<256, 2, true><<<gM0, 256, 0, stream>>>(nullptr, nullptr, X, W0hi, W0lo, Dh, n);
    spmm_kernel<4, true, true><<<gS, 256, 0, stream>>>(Dh, nullptr, HI, LO, rowptr, meta, rnorm, b0, n);
    // D1 ; B = gelu(spmm(D1)+b1) -> bf16 hi/lo
    dense_mfma_kernel<256, 4, false><<<gMd, 256, 0, stream>>>(HI, LO, nullptr, W1hi, W1lo, Dh, n);
    spmm_kernel<4, true, true><<<gS, 256, 0, stream>>>(Dh, nullptr, HI, LO, rowptr, meta, rnorm, b1, n);
    // D2 (128-wide) ; out = spmm(D2) + b2 (fp32)
    dense_mfma_kernel<128, 4, false><<<gMd, 256, 0, stream>>>(HI, LO, nullptr, W2hi, W2lo, Dh, n);
    spmm_kernel<2, false, false><<<gS, 256, 0, stream>>>(Dh, (float*)d_out, nullptr, nullptr, rowptr, meta, rnorm, b2, n);
}

// Round 12
// 782.761 us; speedup vs baseline: 1.2156x; 1.0221x over previous
//
#include <hip/hip_runtime.h>
#include <hip/hip_bf16.h>

// ---------------------------------------------------------------------------
// GCN via associativity:  spmm(H) @ W == spmm(H @ W)
//   D0 = X @ W0T   (f16)  ; A = gelu(spmm(D0) + b0) -> bf16 hi/lo
//   D1 = A @ W1T   (f16)  ; B = gelu(spmm(D1) + b1) -> bf16 hi/lo
//   D2 = B @ W2T   (f16)  ; out = spmm(D2) + b2     (fp32)
// Dense on MFMA via split-bf16 (x = hi+lo, 3 MFMA products, fp32 acc).
// Dense: W staged per 32-k chunk into DOUBLE-BUFFERED LDS via
// global_load_lds; stage(c+1) issued before compute(c), drained by
// vmcnt(0)+raw-barrier AFTER compute -> staging overlaps MFMA.
// SpMM: 2 rows/wave, 32 lanes x f16x8 (16B) gathers -> half the load/addr
// instructions per row. FETCH is at the XCD-replication floor (~406MB).
// ---------------------------------------------------------------------------

typedef float f32x4 __attribute__((ext_vector_type(4)));
typedef float f32x2 __attribute__((ext_vector_type(2)));
typedef short s16x4 __attribute__((ext_vector_type(4)));
typedef short s16x8 __attribute__((ext_vector_type(8)));
typedef short bf16x8 __attribute__((ext_vector_type(8)));
typedef _Float16 h16x8 __attribute__((ext_vector_type(8)));
typedef _Float16 h16x4 __attribute__((ext_vector_type(4)));

__device__ __forceinline__ unsigned short f2bf(float x) {   // RNE
    unsigned u = __float_as_uint(x);
    return (unsigned short)((u + 0x7fff + ((u >> 16) & 1)) >> 16);
}
__device__ __forceinline__ float bf2f(unsigned short b) {
    return __uint_as_float(((unsigned)b) << 16);
}

__device__ __forceinline__ float gelu_fast(float x) {
    float u = 0.7978845608028654f * (x + 0.044715f * x * x * x);
    return x / (1.0f + __expf(-2.0f * u));
}

__global__ void count_kernel(const int* __restrict__ row, int* __restrict__ cnt, int e) {
    int i = blockIdx.x * blockDim.x + threadIdx.x;
    if (i < e) atomicAdd(&cnt[row[i]], 1);
}

__global__ void rnorm_kernel(const int* __restrict__ cnt, float* __restrict__ rnorm, int n) {
    int i = blockIdx.x * blockDim.x + threadIdx.x;
    if (i < n) rnorm[i] = rsqrtf((float)(cnt[i] + 1));
}

__global__ void scan1_kernel(const int* __restrict__ cnt, int* __restrict__ rowptr,
                             int* __restrict__ bsum, int n) {
    __shared__ int s[1024];
    int t = threadIdx.x;
    int i = blockIdx.x * 1024 + t;
    int v = (i < n) ? cnt[i] : 0;
    s[t] = v;
    __syncthreads();
    for (int off = 1; off < 1024; off <<= 1) {
        int x = (t >= off) ? s[t - off] : 0;
        __syncthreads();
        s[t] += x;
        __syncthreads();
    }
    if (i < n) rowptr[i] = s[t] - v;
    if (t == 1023) bsum[blockIdx.x] = s[1023];
}

__global__ void scan2_kernel(int* bsum, int nb) {
    if (threadIdx.x == 0 && blockIdx.x == 0) {
        int a = 0;
        for (int b = 0; b < nb; ++b) { int v = bsum[b]; bsum[b] = a; a += v; }
    }
}

__global__ void scan3_kernel(int* __restrict__ rowptr, const int* __restrict__ bsum, int n, int e) {
    int i = blockIdx.x * blockDim.x + threadIdx.x;
    if (i < n) rowptr[i] += bsum[i >> 10];
    if (i == 0) rowptr[n] = e;
}

__global__ void fill_kernel(const int* __restrict__ row, const int* __restrict__ col,
                            const int* __restrict__ rowptr, int* __restrict__ fillc,
                            const float* __restrict__ rnorm,
                            int2* __restrict__ meta, int e) {
    int i = blockIdx.x * blockDim.x + threadIdx.x;
    if (i >= e) return;
    int r = row[i], c = col[i];
    int pos = rowptr[r] + atomicAdd(&fillc[r], 1);
    float w = rnorm[r] * rnorm[c];
    meta[pos] = make_int2(c, __float_as_int(w));
}

// fp32 -> (bf16 hi, bf16 lo) elementwise (weights only; X split fused in dense)
__global__ void split_kernel(const float* __restrict__ in,
                             unsigned short* __restrict__ hi,
                             unsigned short* __restrict__ lo, int total4) {
    int i = blockIdx.x * blockDim.x + threadIdx.x;
    if (i >= total4) return;
    f32x4 x = *(const f32x4*)(in + (size_t)i * 4);
    s16x4 h, l;
#pragma unroll
    for (int q = 0; q < 4; ++q) {
        unsigned short hb = f2bf(x[q]);
        h[q] = (short)hb;
        l[q] = (short)f2bf(x[q] - bf2f(hb));
    }
    *(s16x4*)(hi + (size_t)i * 4) = h;
    *(s16x4*)(lo + (size_t)i * 4) = l;
}

template <int WPL> struct HVecT;
template <> struct HVecT<8> { using T = h16x8; };
template <> struct HVecT<4> { using T = h16x4; };

// 2 rows per wave: 32 lanes per row, each lane WPL f16 elems (16B/8B gathers).
// fp32 accumulate. Bias + optional gelu fused; SPLIT writes bf16 hi/lo.
template <int WPL, bool GELU, bool SPLIT>
__global__ __launch_bounds__(256) void spmm_kernel(const _Float16* __restrict__ in,
                                                   float* __restrict__ out,
                                                   unsigned short* __restrict__ ohi,
                                                   unsigned short* __restrict__ olo,
                                                   const int* __restrict__ rowptr,
                                                   const int2* __restrict__ meta,
                                                   const float* __restrict__ rnorm,
                                                   const float* __restrict__ bias, int n) {
    using hvec_t = typename HVecT<WPL>::T;
    constexpr int NCOL = 32 * WPL;       // 256 / 128
    int lane = threadIdx.x & 63;
    int sub = lane & 31;
    int wid = blockIdx.x * 8 + ((threadIdx.x >> 6) << 1) + (lane >> 5);
    if (wid >= n) return;
    const _Float16* lanebase = in + sub * WPL;

    float rn = rnorm[wid];
    float sw = rn * rn;   // self-loop weight
    float acc[WPL];
    {
        hvec_t a = *(const hvec_t*)(lanebase + (size_t)wid * NCOL);
#pragma unroll
        for (int q = 0; q < WPL; ++q) acc[q] = sw * (float)a[q];
    }

    int e0 = rowptr[wid], e1 = rowptr[wid + 1];
    int e = e0;
    int nbatch = (e1 - e0) >> 3;
    if (nbatch > 0) {
        int2 m[8];
#pragma unroll
        for (int u = 0; u < 8; ++u) m[u] = meta[e + u];
        for (int b = 0; b < nbatch; ++b) {
            hvec_t v[8];
#pragma unroll
            for (int u = 0; u < 8; ++u) v[u] = *(const hvec_t*)(lanebase + (size_t)m[u].x * NCOL);
            int2 mn[8];
            bool more = (b + 1 < nbatch);
            if (more) {
#pragma unroll
                for (int u = 0; u < 8; ++u) mn[u] = meta[e + 8 + u];
            }
#pragma unroll
            for (int u = 0; u < 8; ++u) {
                float w = __int_as_float(m[u].y);
#pragma unroll
                for (int q = 0; q < WPL; ++q) acc[q] = fmaf(w, (float)v[u][q], acc[q]);
            }
            if (more) {
#pragma unroll
                for (int u = 0; u < 8; ++u) m[u] = mn[u];
            }
            e += 8;
        }
    }
    for (; e < e1; ++e) {
        int2 m = meta[e];
        hvec_t v = *(const hvec_t*)(lanebase + (size_t)m.x * NCOL);
        float w = __int_as_float(m.y);
#pragma unroll
        for (int q = 0; q < WPL; ++q) acc[q] = fmaf(w, (float)v[q], acc[q]);
    }

    float bv[WPL];
#pragma unroll
    for (int q = 0; q < WPL; ++q) bv[q] = bias[sub * WPL + q];

    if (SPLIT) {
        s16x8 h, l;
#pragma unroll
        for (int q = 0; q < WPL; ++q) {
            float x = acc[q] + bv[q];
            float y = GELU ? gelu_fast(x) : x;
            unsigned short hb = f2bf(y);
            h[q] = (short)hb;
            l[q] = (short)f2bf(y - bf2f(hb));
        }
        *(s16x8*)(ohi + (size_t)wid * NCOL + sub * WPL) = h;
        *(s16x8*)(olo + (size_t)wid * NCOL + sub * WPL) = l;
    } else {
        f32x4 o;
#pragma unroll
        for (int q = 0; q < WPL; ++q) {
            float x = acc[q] + bv[q];
            o[q] = GELU ? gelu_fast(x) : x;
        }
        __builtin_nontemporal_store(o, (f32x4*)(out + (size_t)wid * NCOL + sub * WPL));
    }
}

// out[N][DO](f16) = A[N][256] @ (Whi+Wlo)[DO][256]^T via 3 bf16 MFMAs.
// 4 waves = 2 row-groups x 2 col-halves; RT row-frags x DO/2 cols per wave.
// W staged per KC=32 chunk into DOUBLE-BUFFERED LDS via global_load_lds;
// stage(c+1) issued BEFORE compute(c); drained by vmcnt(0) + raw s_barrier
// AFTER compute -> staging overlaps MFMA (T3 2-phase recipe).
template <int DO, int RT, bool SPLITIN>
__global__ __launch_bounds__(256, 2) void dense_mfma_kernel(
        const unsigned short* __restrict__ Ahi, const unsigned short* __restrict__ Alo,
        const float* __restrict__ Af32,
        const unsigned short* __restrict__ Whi, const unsigned short* __restrict__ Wlo,
        _Float16* __restrict__ out, int n) {
    constexpr int KC = 32;
    constexpr int NCH = 256 / KC;        // 8 chunks
    constexpr int NTT = DO / 16;         // total col tiles (16 / 8)
    constexpr int NT = NTT / 2;          // col tiles per wave
    constexpr int NFRAG = 2 * NTT;       // hi+lo frags per chunk (32 / 16)
    constexpr int BM = 2 * RT * 16;      // rows per block
    __shared__ bf16x8 s_w[2][NFRAG * 64]; // 2x32KB (DO=256) / 2x16KB (128)

    int t = threadIdx.x;
    int lane = t & 63;
    int w = t >> 6;
    int r = lane & 15;
    int g = lane >> 4;
    int h = w & 1;                       // col half
    int row0 = blockIdx.x * BM + (w >> 1) * (RT * 16);

    int aoff[RT];
#pragma unroll
    for (int rt = 0; rt < RT; ++rt) {
        int arow = row0 + rt * 16 + r;
        if (arow >= n) arow = n - 1;     // clamp (tail block)
        aoff[rt] = arow * 256 + g * 8;
    }

    f32x4 acc[RT][NT];
#pragma unroll
    for (int rt = 0; rt < RT; ++rt)
#pragma unroll
        for (int nt = 0; nt < NT; ++nt) acc[rt][nt] = (f32x4){0.f, 0.f, 0.f, 0.f};

    auto stage = [&](int c, int b) {
#pragma unroll
        for (int i = 0; i < NFRAG / 4; ++i) {
            int s = t + i * 256;
            int sl = s & 63;
            int f = s >> 6;              // f = op*NTT + ntf
            int ntf = f % NTT;
            int op = f / NTT;
            const unsigned short* src = op ? Wlo : Whi;
            const unsigned short* gsrc =
                &src[(size_t)(ntf * 16 + (sl & 15)) * 256 + c * KC + ((sl >> 4) << 3)];
            __builtin_amdgcn_global_load_lds(
                (const __attribute__((address_space(1))) void*)gsrc,
                (__attribute__((address_space(3))) void*)&s_w[b][s], 16, 0, 0);
        }
    };

    // prologue: stage chunk 0, drain, barrier
    stage(0, 0);
    asm volatile("s_waitcnt vmcnt(0)" ::: "memory");
    __builtin_amdgcn_s_barrier();
    __builtin_amdgcn_sched_barrier(0);

    for (int c = 0; c < NCH; ++c) {
        int b = c & 1;
        if (c + 1 < NCH) stage(c + 1, b ^ 1);   // overlaps with compute below

        // A fragments for this chunk (compiler inserts waits before MFMA use)
        bf16x8 ah[RT], al[RT];
#pragma unroll
        for (int rt = 0; rt < RT; ++rt) {
            if (SPLITIN) {
                f32x4 x0 = *(const f32x4*)&Af32[aoff[rt] + c * KC];
                f32x4 x1 = *(const f32x4*)&Af32[aoff[rt] + c * KC + 4];
#pragma unroll
                for (int q = 0; q < 4; ++q) {
                    unsigned short hb = f2bf(x0[q]);
                    ah[rt][q] = (short)hb;
                    al[rt][q] = (short)f2bf(x0[q] - bf2f(hb));
                    unsigned short hb1 = f2bf(x1[q]);
                    ah[rt][q + 4] = (short)hb1;
                    al[rt][q + 4] = (short)f2bf(x1[q] - bf2f(hb1));
                }
            } else {
                ah[rt] = *(const bf16x8*)&Ahi[aoff[rt] + c * KC];
                al[rt] = *(const bf16x8*)&Alo[aoff[rt] + c * KC];
            }
        }

#pragma unroll
        for (int nt = 0; nt < NT; ++nt) {
            int ntf = h * NT + nt;
            bf16x8 wh = s_w[b][ntf * 64 + lane];
            bf16x8 wl = s_w[b][(NTT + ntf) * 64 + lane];
#pragma unroll
            for (int rt = 0; rt < RT; ++rt) {
                acc[rt][nt] = __builtin_amdgcn_mfma_f32_16x16x32_bf16(ah[rt], wh, acc[rt][nt], 0, 0, 0);
                acc[rt][nt] = __builtin_amdgcn_mfma_f32_16x16x32_bf16(ah[rt], wl, acc[rt][nt], 0, 0, 0);
                acc[rt][nt] = __builtin_amdgcn_mfma_f32_16x16x32_bf16(al[rt], wh, acc[rt][nt], 0, 0, 0);
            }
        }

        if (c + 1 < NCH) {
            asm volatile("s_waitcnt vmcnt(0)" ::: "memory");   // stage(c+1) landed
            __builtin_amdgcn_sched_barrier(0);
            __builtin_amdgcn_s_barrier();
            __builtin_amdgcn_sched_barrier(0);
        }
    }

    // C frag: col=lane&15 (=r), row=g*4+j within each 16-row tile
#pragma unroll
    for (int rt = 0; rt < RT; ++rt) {
#pragma unroll
        for (int nt = 0; nt < NT; ++nt) {
            int ccol = (h * NT + nt) * 16 + r;
#pragma unroll
            for (int j = 0; j < 4; ++j) {
                int rr = row0 + rt * 16 + g * 4 + j;
                if (rr < n) out[(size_t)rr * DO + ccol] = (_Float16)acc[rt][nt][j];
            }
        }
    }
}

extern "C" void kernel_launch(void* const* d_in, const int* in_sizes, int n_in,
                              void* d_out, int out_size, void* d_ws, size_t ws_size,
                              hipStream_t stream) {
    const float* X  = (const float*)d_in[0];
    const int* row  = (const int*)d_in[1];
    const int* col  = (const int*)d_in[2];
    const float* W0 = (const float*)d_in[3];
    const float* b0 = (const float*)d_in[4];
    const float* W1 = (const float*)d_in[5];
    const float* b1 = (const float*)d_in[6];
    const float* W2 = (const float*)d_in[7];
    const float* b2 = (const float*)d_in[8];

    int n = in_sizes[0] / 256;   // 100000
    int e = in_sizes[1];         // 1600000

    char* ws = (char*)d_ws;
    size_t off = 0;
    auto alloc = [&](size_t bytes) {
        void* p = ws + off;
        off += (bytes + 255) & ~(size_t)255;
        return p;
    };
    unsigned short* HI   = (unsigned short*)alloc((size_t)n * 256 * 2);
    unsigned short* LO   = (unsigned short*)alloc((size_t)n * 256 * 2);
    _Float16*       Dh   = (_Float16*)alloc((size_t)n * 256 * 2);
    unsigned short* W0hi = (unsigned short*)alloc(256 * 256 * 2);
    unsigned short* W0lo = (unsigned short*)alloc(256 * 256 * 2);
    unsigned short* W1hi = (unsigned short*)alloc(256 * 256 * 2);
    unsigned short* W1lo = (unsigned short*)alloc(256 * 256 * 2);
    unsigned short* W2hi = (unsigned short*)alloc(256 * 128 * 2);
    unsigned short* W2lo = (unsigned short*)alloc(256 * 128 * 2);
    int*   cnt    = (int*)alloc((size_t)n * 4);
    int*   fillc  = (int*)alloc((size_t)n * 4);
    float* rnorm  = (float*)alloc((size_t)n * 4);
    int*   rowptr = (int*)alloc(((size_t)n + 1) * 4);
    int*   bsum   = (int*)alloc(512);
    int2*  meta   = (int2*)alloc((size_t)e * 8);

    (void)hipMemsetAsync(cnt, 0, (size_t)n * 4, stream);
    (void)hipMemsetAsync(fillc, 0, (size_t)n * 4, stream);

    int gE = (e + 255) / 256;
    int gN = (n + 255) / 256;
    int nb = (n + 1023) / 1024;

    count_kernel<<<gE, 256, 0, stream>>>(row, cnt, e);
    rnorm_kernel<<<gN, 256, 0, stream>>>(cnt, rnorm, n);
    scan1_kernel<<<nb, 1024, 0, stream>>>(cnt, rowptr, bsum, n);
    scan2_kernel<<<1, 64, 0, stream>>>(bsum, nb);
    scan3_kernel<<<gN, 256, 0, stream>>>(rowptr, bsum, n, e);
    fill_kernel<<<gE, 256, 0, stream>>>(row, col, rowptr, fillc, rnorm, meta, e);

    split_kernel<<<(16384 + 255) / 256, 256, 0, stream>>>(W0, W0hi, W0lo, 16384);
    split_kernel<<<(16384 + 255) / 256, 256, 0, stream>>>(W1, W1hi, W1lo, 16384);
    split_kernel<<<(8192 + 255) / 256, 256, 0, stream>>>(W2, W2hi, W2lo, 8192);

    int gS  = (n + 7) / 8;        // spmm: 4 waves/block, 2 rows/wave
    int gM0 = (n + 63) / 64;      // dense0: BM=64  (RT=2, fp32 X split fused)
    int gMd = (n + 127) / 128;    // dense1/2: BM=128 (RT=4)

    // D0 = X @ W0T (X split in-register) ; A = gelu(spmm(D0)+b0) -> bf16 hi/lo
    dense_mfma_kernel<256, 2, true><<<gM0, 256, 0, stream>>>(nullptr, nullptr, X, W0hi, W0lo, Dh, n);
    spmm_kernel<8, true, true><<<gS, 256, 0, stream>>>(Dh, nullptr, HI, LO, rowptr, meta, rnorm, b0, n);
    // D1 ; B = gelu(spmm(D1)+b1) -> bf16 hi/lo
    dense_mfma_kernel<256, 4, false><<<gMd, 256, 0, stream>>>(HI, LO, nullptr, W1hi, W1lo, Dh, n);
    spmm_kernel<8, true, true><<<gS, 256, 0, stream>>>(Dh, nullptr, HI, LO, rowptr, meta, rnorm, b1, n);
    // D2 (128-wide) ; out = spmm(D2) + b2 (fp32)
    dense_mfma_kernel<128, 4, false><<<gMd, 256, 0, stream>>>(HI, LO, nullptr, W2hi, W2lo, Dh, n);
    spmm_kernel<4, false, false><<<gS, 256, 0, stream>>>(Dh, (float*)d_out, nullptr, nullptr, rowptr, meta, rnorm, b2, n);
}